// Round 13
// baseline (1142.885 us; speedup 1.0000x reference)
//
#include <hip/hip_runtime.h>

#define N_ROWS 65536
#define DIM    512
#define NSTEP  10

typedef float  f32x16 __attribute__((ext_vector_type(16)));
typedef float  f32x4  __attribute__((ext_vector_type(4)));
typedef short  s16x8  __attribute__((ext_vector_type(8)));
typedef __bf16 bf16x8 __attribute__((ext_vector_type(8)));
typedef unsigned int u32x2 __attribute__((ext_vector_type(2)));
typedef unsigned int u32x4 __attribute__((ext_vector_type(4)));

__device__ __forceinline__ unsigned f2bf(float f) {
  unsigned u = __float_as_uint(f);
  return (u + 0x7fffu + ((u >> 16) & 1u)) >> 16;  // exact RNE fp32 -> bf16
}
// nearest rounding (ties away from zero), packed via v_perm
__device__ __forceinline__ unsigned pack2bf_rn(float a, float b) {
  unsigned ua = __float_as_uint(a) + 0x8000u;
  unsigned ub = __float_as_uint(b) + 0x8000u;
  return __builtin_amdgcn_perm(ub, ua, 0x07060302u);
}
#define LOG2E_X2 2.885390081777927f
#define LOG2E    1.442695040888963f
__device__ __forceinline__ float ftanh(float x) {   // 1 - 2/(1+2^(2x*log2e))
  float t = __builtin_amdgcn_exp2f(x * LOG2E_X2);
  float r = __builtin_amdgcn_rcpf(1.0f + t);
  return __builtin_fmaf(-2.0f, r, 1.0f);
}
__device__ __forceinline__ float fsigm(float x) {
  float t = __builtin_amdgcn_exp2f(-x * LOG2E);
  return __builtin_amdgcn_rcpf(1.0f + t);
}
__device__ __forceinline__ void mfma(f32x16& c, s16x8 a, s16x8 b) {
  c = __builtin_amdgcn_mfma_f32_32x32x16_bf16(
        __builtin_bit_cast(bf16x8, a), __builtin_bit_cast(bf16x8, b), c, 0, 0, 0);
}

// Pack a 512x512 slice of row-major fp32 weights into bf16 MFMA A-frags,
// OTG-MAJOR streams: frag f = otg*32 + ks holds
// A[o=otg*32+(l&31)][k=ks*16+8*(l>>5)+i], i=0..7.
__global__ void pack_frags_kernel(const float* __restrict__ src, int row_stride,
                                  int col_off, unsigned short* __restrict__ dst) {
  const int idx = blockIdx.x * 256 + threadIdx.x;  // 0..32767
  const int l    = idx & 63;
  const int frag = idx >> 6;        // otg*32 + ks
  const int otg  = frag >> 5;
  const int ks   = frag & 31;
  const int o = otg * 32 + (l & 31);
  const int k = ks * 16 + (l >> 5) * 8;
  const float* p = src + (size_t)o * row_stride + col_off + k;
  s16x8 v;
#pragma unroll
  for (int i = 0; i < 8; ++i) v[i] = (short)f2bf(p[i]);
  *reinterpret_cast<s16x8*>(dst + (size_t)idx * 8) = v;
}

// c1[s][o] = b1[o] + t_s * W1[o][512]   (time-column folded into step bias)
__global__ void c1_kernel(const float* __restrict__ W1, const float* __restrict__ b1,
                          float* __restrict__ c1) {
  const int o = threadIdx.x;  // 512 threads
  const float wt = W1[(size_t)o * 513 + 512];
  const float bb = b1[o];
  for (int s = 0; s < NSTEP; ++s)
    c1[s * DIM + o] = bb + ((float)s * 0.1f) * wt;
}

// 32-ROW blocks: 2048 blocks x 512 thr (8 waves). Wave w owns o-cols
// [64w,64w+64) x 32 m rows -> acc = 2 frags (32 AGPR) + hst fp32 (32 VGPR).
// Total regs ~96-110 <= 128 -> TWO independent blocks/CU (cross-block
// latency hiding, m114). Double-buffered 32KB frag-layout tiles: frag ks @
// ks*1024, lane l's 16B = tile[m=(l&31)][k=16ks+8*(l>>5)+i].
__global__ __launch_bounds__(512, 4)
void ode_fused(const float* __restrict__ x, const float* __restrict__ h0,
               const float* __restrict__ b2, const float* __restrict__ bg,
               const s16x8* __restrict__ w1f, const s16x8* __restrict__ w2f,
               const s16x8* __restrict__ wgaf, const s16x8* __restrict__ wgbf,
               const float* __restrict__ c1, float* __restrict__ out)
{
  __shared__ char ldsA[32 * 1024];   // 32 frags of 1KB
  __shared__ char ldsB[32 * 1024];

  const int tid = threadIdx.x;
  const int w   = tid >> 6;          // wave 0..7
  const int l   = tid & 63;
  const int lm  = l & 31;
  const int h5  = l >> 5;
  const int m0  = blockIdx.x << 5;   // 32 rows per block
  const int ow  = w << 6;            // 64-wide o-column range
  const unsigned lbyte = (unsigned)l << 4;

  // ---------------- stage h0 -> ldsA in frag layout (4 frags/wave) --------
  {
#pragma unroll
    for (int q = 0; q < 4; ++q) {
      const int ks = (w << 2) | q;
      const float* src = h0 + (size_t)(m0 + lm) * DIM + (ks << 4) + (h5 << 3);
      f32x4 v0 = *reinterpret_cast<const f32x4*>(src);
      f32x4 v1 = *reinterpret_cast<const f32x4*>(src + 4);
      u32x4 pk;
      pk[0] = pack2bf_rn(v0[0], v0[1]); pk[1] = pack2bf_rn(v0[2], v0[3]);
      pk[2] = pack2bf_rn(v1[0], v1[1]); pk[3] = pack2bf_rn(v1[2], v1[3]);
      *reinterpret_cast<u32x4*>(ldsA + (ks << 10) + lbyte) = pk;
    }
  }

  // ---------------- fp32 h state (32 regs) ----------------
  // value (ot, i=4g+j): o = ow+32*ot+8g+4*h5+j, m = m0+lm
  f32x16 hst[2];
  {
    const float* hr = h0 + (size_t)(m0 + lm) * DIM;
#pragma unroll
    for (int ot = 0; ot < 2; ++ot)
#pragma unroll
      for (int g = 0; g < 4; ++g) {
        const int oc = ow + (ot << 5) + (g << 3) + (h5 << 2);
        f32x4 v = *reinterpret_cast<const f32x4*>(hr + oc);
#pragma unroll
        for (int j = 0; j < 4; ++j) hst[ot][(g << 2) + j] = v[j];
      }
  }

  f32x16 acc[2];

  // acc[ot][o][m] += W[o][k]*tile[m][k], K=512. Address-free, rolled.
  auto mm_lds = [&](const s16x8* __restrict__ A, const char* __restrict__ buf) {
    const s16x8* A0 = A + (w << 12);   // otg=2w stream
    const s16x8* A1 = A0 + 2048;       // otg=2w+1 stream
#pragma unroll 4
    for (int ks = 0; ks < 32; ++ks) {
      s16x8 a0 = A0[(ks << 6) + l];
      s16x8 a1 = A1[(ks << 6) + l];
      s16x8 b = *reinterpret_cast<const s16x8*>(buf + (ks << 10) + lbyte);
      mfma(acc[0], a0, b);
      mfma(acc[1], a1, b);
    }
  };

  // broadcast per-o fp32 vector into acc
  auto acc_init = [&](const float* __restrict__ vec) {
#pragma unroll
    for (int ot = 0; ot < 2; ++ot)
#pragma unroll
      for (int g = 0; g < 4; ++g) {
        const int oc = ow + (ot << 5) + (g << 3) + (h5 << 2);
        f32x4 v = *reinterpret_cast<const f32x4*>(vec + oc);
#pragma unroll
        for (int j = 0; j < 4; ++j) acc[ot][(g << 2) + j] = v[j];
      }
  };

  // write bf16(src) into frag layout (k-dim = wave's o-cols).
  // value (ot,4g+j) -> frag ks=4w+2ot+(g>>1), lane lm+32*(g&1), byte 8*h5
  const unsigned twbase = ((unsigned)w << 12) + ((unsigned)lm << 4) + ((unsigned)h5 << 3);
  auto tile_write = [&](const f32x16 src[2], char* __restrict__ buf) {
#pragma unroll
    for (int ot = 0; ot < 2; ++ot)
#pragma unroll
      for (int g = 0; g < 4; ++g) {
        u32x2 pk;
        pk[0] = pack2bf_rn(src[ot][(g << 2) + 0], src[ot][(g << 2) + 1]);
        pk[1] = pack2bf_rn(src[ot][(g << 2) + 2], src[ot][(g << 2) + 3]);
        *reinterpret_cast<u32x2*>(buf + twbase + (ot << 11) + ((g >> 1) << 10)
                                  + ((g & 1) << 9)) = pk;
      }
  };

  __syncthreads();  // staged tile visible

#pragma unroll 1
  for (int s = 0; s < NSTEP; ++s) {
    // H1 = tanh(W1 . Z^T + c1_s)     (read A, write B)
    acc_init(c1 + s * DIM);
    mm_lds(w1f, ldsA);
#pragma unroll
    for (int ot = 0; ot < 2; ++ot)
#pragma unroll
      for (int i = 0; i < 16; ++i) acc[ot][i] = ftanh(acc[ot][i]);
    tile_write(acc, ldsB);
    __syncthreads();          // B complete; A-reads already done
    // h += dt * tanh(W2 . H1^T + b2)  (read B, write A)
    acc_init(b2);
    mm_lds(w2f, ldsB);
#pragma unroll
    for (int ot = 0; ot < 2; ++ot)
#pragma unroll
      for (int i = 0; i < 16; ++i) {
        float t = __builtin_amdgcn_exp2f(acc[ot][i] * LOG2E_X2);
        float r = __builtin_amdgcn_rcpf(1.0f + t);
        hst[ot][i] = __builtin_fmaf(-0.2f, r, hst[ot][i] + 0.1f);
      }
    tile_write(hst, ldsA);
    __syncthreads();          // A complete
  }

  // ---- gating: G = WgB . E^T + WgA . X^T + bg ----
  acc_init(bg);
  mm_lds(wgbf, ldsA);  // evolved part (ldsA holds E)
  {
    const s16x8* A0 = wgaf + (w << 12);
    const s16x8* A1 = A0 + 2048;
    const float* xr = x + (size_t)(m0 + lm) * DIM + (h5 << 3);
#pragma unroll 4
    for (int ks = 0; ks < 32; ++ks) {
      s16x8 a0 = A0[(ks << 6) + l];
      s16x8 a1 = A1[(ks << 6) + l];
      const int kc = ks << 4;
      f32x4 u0 = *reinterpret_cast<const f32x4*>(xr + kc);
      f32x4 u1 = *reinterpret_cast<const f32x4*>(xr + kc + 4);
      u32x4 pb;
      pb[0] = pack2bf_rn(u0[0], u0[1]); pb[1] = pack2bf_rn(u0[2], u0[3]);
      pb[2] = pack2bf_rn(u1[0], u1[1]); pb[3] = pack2bf_rn(u1[2], u1[3]);
      s16x8 b = __builtin_bit_cast(s16x8, pb);
      mfma(acc[0], a0, b);
      mfma(acc[1], a1, b);
    }
  }

  // ---- blend + store both output copies ----
  float* out1 = out + (size_t)N_ROWS * DIM;
  {
    const int m = m0 + lm;
    const float* xr = x + (size_t)m * DIM;
    float* o0p = out  + (size_t)m * DIM;
    float* o1p = out1 + (size_t)m * DIM;
#pragma unroll
    for (int ot = 0; ot < 2; ++ot)
#pragma unroll
      for (int g = 0; g < 4; ++g) {
        const int oc = ow + (ot << 5) + (g << 3) + (h5 << 2);
        f32x4 xv = *reinterpret_cast<const f32x4*>(xr + oc);
        f32x4 r;
#pragma unroll
        for (int j = 0; j < 4; ++j) {
          const float gt = fsigm(acc[ot][(g << 2) + j]);
          const float ev = hst[ot][(g << 2) + j];
          r[j] = gt * ev + (1.0f - gt) * xv[j];
        }
        *reinterpret_cast<f32x4*>(o0p + oc) = r;
        *reinterpret_cast<f32x4*>(o1p + oc) = r;
      }
  }
}

extern "C" void kernel_launch(void* const* d_in, const int* in_sizes, int n_in,
                              void* d_out, int out_size, void* d_ws, size_t ws_size,
                              hipStream_t stream) {
  const float* x  = (const float*)d_in[0];
  const float* h0 = (const float*)d_in[1];
  const float* W1 = (const float*)d_in[2];
  const float* b1 = (const float*)d_in[3];
  const float* W2 = (const float*)d_in[4];
  const float* b2 = (const float*)d_in[5];
  const float* Wg = (const float*)d_in[6];
  const float* bg = (const float*)d_in[7];

  char* ws = (char*)d_ws;
  const size_t FRAG_BYTES = (size_t)512 * 512 * 2;  // 512 KB each
  unsigned short* w1f  = (unsigned short*)(ws + 0 * FRAG_BYTES);
  unsigned short* w2f  = (unsigned short*)(ws + 1 * FRAG_BYTES);
  unsigned short* wgaf = (unsigned short*)(ws + 2 * FRAG_BYTES);
  unsigned short* wgbf = (unsigned short*)(ws + 3 * FRAG_BYTES);
  float*          c1   = (float*)(ws + 4 * FRAG_BYTES);

  pack_frags_kernel<<<128, 256, 0, stream>>>(W1, 513, 0,   w1f);
  pack_frags_kernel<<<128, 256, 0, stream>>>(W2, 512, 0,   w2f);
  pack_frags_kernel<<<128, 256, 0, stream>>>(Wg, 1024, 0,  wgaf);
  pack_frags_kernel<<<128, 256, 0, stream>>>(Wg, 1024, 512, wgbf);
  c1_kernel<<<1, 512, 0, stream>>>(W1, b1, c1);

  ode_fused<<<N_ROWS / 32, 512, 0, stream>>>(x, h0, b2, bg,
                                             (const s16x8*)w1f, (const s16x8*)w2f,
                                             (const s16x8*)wgaf, (const s16x8*)wgbf,
                                             c1, (float*)d_out);
}